// Round 6
// baseline (76.473 us; speedup 1.0000x reference)
//
#include <hip/hip_runtime.h>
#include <math.h>

// Bahdanau attention, fp32. B=4, TQ=TV=256, H=D=512, U=256.
// out = [context (4*256*512)] ++ [attn (4*256*256)]
//
// tanh(x) = 1 - 2/(e^{2x}+1); e^{2(q+v)} = e^{2q}*e^{2v}.
// proj_partial: K-split GEMMs -> Pq[q][u] partials and PvT[u][vg] partials.
// proj_combine: E = exp2(C*(sum partials + bias)) for Eq and EvT.
// fused_attn: score (1 rcp + fma per element), softmax, context.
// R6 change: per-wave ILP. Score preloads all 32 EvT values to regs (one
// latency exposure, not 8); context double-buffers values loads. The 16
// waves of the one resident block/CU move in lockstep, so latency must be
// hidden WITHIN a wave, not by TLP (R4 showed more waves don't help).

typedef float f4 __attribute__((ext_vector_type(4)));
typedef float f2 __attribute__((ext_vector_type(2)));

#define B_    4
#define TQ_   256
#define TV_   256
#define D_    512
#define U_    256
#define KDIM  512          // H == D == 512
#define MROWS 1024         // B*TQ == B*TV
#define BKP   32           // proj LDS K-tile
#define KQ    128          // proj K-split quarter
#define NSTEP (KQ / BKP)   // 4

#define C2LOG2E 2.8853900817779268f   // 2*log2(e)

// ws layout (f4 units of 65536 per 1024x256 buffer):
//   [0..3] Pq partials [q][u] | [4..7] PvT partials [u][vg] | [8] Eq | [9] EvT
#define PELEMS  262144
#define EQ_OFF  (8 * PELEMS)
#define EVT_OFF (9 * PELEMS)

#if __has_builtin(__builtin_amdgcn_exp2f)
#define EXP2F(x) __builtin_amdgcn_exp2f(x)
#else
#define EXP2F(x) exp2f(x)
#endif
#if __has_builtin(__builtin_amdgcn_rcpf)
#define RCPF(x) __builtin_amdgcn_rcpf(x)
#else
#define RCPF(x) (1.0f / (x))
#endif

// ---------------- K-split projection GEMMs ----------------
__global__ __launch_bounds__(256) void proj_partial(
    const float* __restrict__ query, const float* __restrict__ values,
    const float* __restrict__ W1, const float* __restrict__ W2,
    float* __restrict__ ws)
{
    const int proj = blockIdx.z;    // 0: Pq, 1: PvT
    const int ks   = blockIdx.y;    // K-quarter
    const int tile = blockIdx.x;    // 0..63

    __shared__ __align__(16) float As[BKP][68];
    __shared__ __align__(16) float Bs[BKP][68];

    const int tid = threadIdx.x;
    const int tx = tid & 15, ty = tid >> 4;
    const int trow = tid >> 2, tk = (tid & 3) * 8;   // T-path: 64 rows x 8 k
    const int dk = tid >> 3, dcol = (tid & 7) * 8;   // D-path: 32 k x 64 cols
    const int kb = ks * KQ;

    int m0, n0;
    const float* Tsrc;
    const float* Dsrc;
    if (proj == 0) {
        m0 = (tile >> 2) * 64;  n0 = (tile & 3) * 64;
        Tsrc = query  + (size_t)(m0 + trow) * KDIM + kb + tk;  // -> As[k][m]
        Dsrc = W1     + (size_t)(kb + dk) * U_ + n0 + dcol;    // -> Bs[k][n]
    } else {
        m0 = (tile & 3) * 64;   n0 = (tile >> 2) * 64;
        Tsrc = values + (size_t)(n0 + trow) * KDIM + kb + tk;  // -> Bs[k][n]
        Dsrc = W2     + (size_t)(kb + dk) * U_ + m0 + dcol;    // -> As[k][m]
    }

    f4 t0 = *(const f4*)(Tsrc);
    f4 t1 = *(const f4*)(Tsrc + 4);
    f4 d0 = *(const f4*)(Dsrc);
    f4 d1 = *(const f4*)(Dsrc + 4);

    float acc[4][4] = {};

    for (int s = 0; s < NSTEP; ++s) {
        __syncthreads();
        if (proj == 0) {
            #pragma unroll
            for (int j = 0; j < 4; ++j) {
                As[tk + j][trow]     = t0[j];
                As[tk + 4 + j][trow] = t1[j];
            }
            *(f4*)&Bs[dk][dcol]     = d0;
            *(f4*)&Bs[dk][dcol + 4] = d1;
        } else {
            #pragma unroll
            for (int j = 0; j < 4; ++j) {
                Bs[tk + j][trow]     = t0[j];
                Bs[tk + 4 + j][trow] = t1[j];
            }
            *(f4*)&As[dk][dcol]     = d0;
            *(f4*)&As[dk][dcol + 4] = d1;
        }
        __syncthreads();

        if (s + 1 < NSTEP) {   // prefetch next K-tile into regs
            const float* Tn = Tsrc + (s + 1) * BKP;
            const float* Dn = Dsrc + (size_t)(s + 1) * BKP * U_;
            t0 = *(const f4*)(Tn);
            t1 = *(const f4*)(Tn + 4);
            d0 = *(const f4*)(Dn);
            d1 = *(const f4*)(Dn + 4);
        }

        #pragma unroll
        for (int kk = 0; kk < BKP; ++kk) {
            f4 av = *(const f4*)&As[kk][ty * 4];
            f4 bv = *(const f4*)&Bs[kk][tx * 4];
            #pragma unroll
            for (int i = 0; i < 4; ++i)
                #pragma unroll
                for (int j = 0; j < 4; ++j)
                    acc[i][j] = fmaf(av[i], bv[j], acc[i][j]);
        }
    }

    const int cstride = proj ? MROWS : U_;
    float* P = ws + (size_t)(proj * 4 + ks) * PELEMS;
    #pragma unroll
    for (int i = 0; i < 4; ++i) {
        f4 o = {acc[i][0], acc[i][1], acc[i][2], acc[i][3]};
        *(f4*)&P[(size_t)(m0 + ty * 4 + i) * cstride + n0 + tx * 4] = o;
    }
}

// ---------------- combine: E = exp2(C * (sum of 4 partials + bias)) ----------
__global__ __launch_bounds__(256) void proj_combine(
    const float* __restrict__ b1, const float* __restrict__ b2,
    float* __restrict__ ws)
{
    const int g = blockIdx.x * 256 + threadIdx.x;   // 0..131071
    const int proj = g >> 16;
    const int rem  = g & 65535;
    f4* wsf4 = (f4*)ws;

    f4 p = wsf4[(size_t)(proj * 4)     * 65536 + rem];
    p   += wsf4[(size_t)(proj * 4 + 1) * 65536 + rem];
    p   += wsf4[(size_t)(proj * 4 + 2) * 65536 + rem];
    p   += wsf4[(size_t)(proj * 4 + 3) * 65536 + rem];

    f4 bias;
    if (proj == 0) {
        bias = ((const f4*)b1)[rem & 63];           // u = column
    } else {
        float bb = b2[rem >> 8];                    // u = row (256 f4/row)
        bias = f4{bb, bb, bb, bb};
    }

    f4 e;
    #pragma unroll
    for (int j = 0; j < 4; ++j)
        e[j] = EXP2F((p[j] + bias[j]) * C2LOG2E);

    wsf4[(size_t)(8 + proj) * 65536 + rem] = e;
}

// ---------------- fused score + softmax + context ----------------
// One block = (batch b, 4 q rows). 1024 threads (16 waves).
// Score: thread owns v-pair, 32-u slice; ALL 32 EvT f2 preloaded to regs.
// Softmax: wave w < 4 handles q-row w. Context: quarter-block per q-row,
// double-buffered values prefetch (8 loads in flight).
__global__ __launch_bounds__(1024) void fused_attn(
    const float* __restrict__ values, const float* __restrict__ Vw,
    const float* __restrict__ ws, float* __restrict__ out)
{
    __shared__ __align__(16) f4    eqT[U_];          // {eq[q0+0..3]}[u]
    __shared__ __align__(16) float vw[U_];
    __shared__ __align__(16) float scr[8][4][TV_];   // [u-slice][q][v]

    const float* Eq  = ws + EQ_OFF;
    const float* EvT = ws + EVT_OFF;

    const int tid = threadIdx.x;
    const int b  = blockIdx.y;
    const int q0 = blockIdx.x * 4;

    if (tid < U_) {
        const int u = tid;
        const size_t base = (size_t)(b * TQ_ + q0) * U_ + u;   // 4 coalesced rows
        f4 e = {Eq[base], Eq[base + U_], Eq[base + 2 * U_], Eq[base + 3 * U_]};
        eqT[u] = e;
        vw[u]  = Vw[u];
    }

    // ---- score loads FIRST (before the barrier): 32 f2 in flight per thread
    const int v2 = tid & 127;        // owns v = {2*v2, 2*v2+1}
    const int us = tid >> 7;         // u-slice 0..7 (32 u each)
    const f2* evbase = (const f2*)(EvT + (size_t)b * TV_) + v2
                       + (size_t)(us * 32) * (MROWS / 2);
    f2 ev[32];
    #pragma unroll
    for (int i = 0; i < 32; ++i)
        ev[i] = evbase[(size_t)i * (MROWS / 2)];

    __syncthreads();

    // ---- scores: p(q,v) = sum_u vw[u] * rcp(eq[q,u]*ev[v,u] + 1)
    {
        f2 acc[4] = {{0.f, 0.f}, {0.f, 0.f}, {0.f, 0.f}, {0.f, 0.f}};
        #pragma unroll
        for (int i = 0; i < 32; ++i) {
            const int u = us * 32 + i;
            f4 eq = eqT[u];                            // LDS broadcast
            float w = vw[u];                           // LDS broadcast
            #pragma unroll
            for (int q = 0; q < 4; ++q) {
                float den0 = fmaf(eq[q], ev[i].x, 1.0f);
                float den1 = fmaf(eq[q], ev[i].y, 1.0f);
                acc[q].x = fmaf(w, RCPF(den0), acc[q].x);
                acc[q].y = fmaf(w, RCPF(den1), acc[q].y);
            }
        }
        #pragma unroll
        for (int q = 0; q < 4; ++q)
            *(f2*)&scr[us][q][2 * v2] = acc[q];
    }
    __syncthreads();

    // ---- softmax over v: wave w in [0,4) handles q-row w
    {
        const int w = tid >> 6, lane = tid & 63;
        if (w < 4) {
            float p0 = 0.f, p1 = 0.f, p2 = 0.f, p3 = 0.f;
            #pragma unroll
            for (int s = 0; s < 8; ++s) {
                p0 += scr[s][w][lane];
                p1 += scr[s][w][lane + 64];
                p2 += scr[s][w][lane + 128];
                p3 += scr[s][w][lane + 192];
            }
            float m = fminf(fminf(p0, p1), fminf(p2, p3));  // max score = min p
            #pragma unroll
            for (int off = 32; off; off >>= 1) m = fminf(m, __shfl_xor(m, off));
            float e0 = EXP2F((m - p0) * C2LOG2E);
            float e1 = EXP2F((m - p1) * C2LOG2E);
            float e2 = EXP2F((m - p2) * C2LOG2E);
            float e3 = EXP2F((m - p3) * C2LOG2E);
            float sum = e0 + e1 + e2 + e3;
            #pragma unroll
            for (int off = 32; off; off >>= 1) sum += __shfl_xor(sum, off);
            const float rinv = 1.0f / sum;    // exact division
            e0 *= rinv; e1 *= rinv; e2 *= rinv; e3 *= rinv;
            scr[0][w][lane]       = e0;
            scr[0][w][lane + 64]  = e1;
            scr[0][w][lane + 128] = e2;
            scr[0][w][lane + 192] = e3;
            float* attn_out = out + (size_t)B_ * TQ_ * D_;
            const size_t rb = ((size_t)(b * TQ_ + q0 + w)) * TV_;
            attn_out[rb + lane]       = e0;
            attn_out[rb + lane + 64]  = e1;
            attn_out[rb + lane + 128] = e2;
            attn_out[rb + lane + 192] = e3;
        }
    }
    __syncthreads();

    // ---- context: quarter-block qh owns q-row qh; thread owns d-pair.
    // Double-buffered prefetch: 8 values-loads in flight while 16 FMAs retire.
    {
        const int qh = tid >> 8;
        const int d2 = tid & 255;
        const f2* vp = (const f2*)&values[(size_t)b * TV_ * D_] + d2;
        const float* arow = &scr[0][qh][0];

        f2 bufA[8], bufB[8];
        #pragma unroll
        for (int i = 0; i < 8; ++i) bufA[i] = vp[(size_t)i * (D_ / 2)];

        f2 acc = {0.f, 0.f};
        #pragma unroll
        for (int g = 0; g < 32; g += 2) {
            if (g + 1 < 32) {
                #pragma unroll
                for (int i = 0; i < 8; ++i)
                    bufB[i] = vp[(size_t)((g + 1) * 8 + i) * (D_ / 2)];
            }
            #pragma unroll
            for (int i = 0; i < 8; ++i)
                acc += arow[g * 8 + i] * bufA[i];
            if (g + 2 < 32) {
                #pragma unroll
                for (int i = 0; i < 8; ++i)
                    bufA[i] = vp[(size_t)((g + 2) * 8 + i) * (D_ / 2)];
            }
            #pragma unroll
            for (int i = 0; i < 8; ++i)
                acc += arow[(g + 1) * 8 + i] * bufB[i];
        }
        *(f2*)&out[((size_t)(b * TQ_ + q0 + qh)) * D_ + 2 * d2] = acc;
    }
}

extern "C" void kernel_launch(void* const* d_in, const int* in_sizes, int n_in,
                              void* d_out, int out_size, void* d_ws, size_t ws_size,
                              hipStream_t stream) {
    const float* query  = (const float*)d_in[0];
    const float* values = (const float*)d_in[1];
    const float* W1     = (const float*)d_in[2];
    const float* b1     = (const float*)d_in[3];
    const float* W2     = (const float*)d_in[4];
    const float* b2     = (const float*)d_in[5];
    const float* Vw     = (const float*)d_in[6];
    float* out = (float*)d_out;
    float* ws  = (float*)d_ws;

    proj_partial<<<dim3(64, 4, 2), 256, 0, stream>>>(query, values, W1, W2, ws);
    proj_combine<<<dim3(512), 256, 0, stream>>>(b1, b2, ws);
    fused_attn<<<dim3(TQ_ / 4, B_), 1024, 0, stream>>>(values, Vw, ws, out);
}

// Round 7
// 69.137 us; speedup vs baseline: 1.1061x; 1.1061x over previous
//
#include <hip/hip_runtime.h>
#include <math.h>

// Bahdanau attention, fp32. B=4, TQ=TV=256, H=D=512, U=256.
// out = [context (4*256*512)] ++ [attn (4*256*256)]
//
// tanh(x) = 1 - 2/(e^{2x}+1); e^{2(q+v)} = e^{2q}*e^{2v}.
// proj_partial: K-split GEMMs -> Pq[q][u] partials and PvT[u][vg] partials.
// proj_combine: E = exp2(C*(sum partials + bias)) for Eq and EvT.
// fused_attn: score (1 rcp + 2 fma per element), softmax, context.
//
// R7: R6's reg-pipelining was invalidated by scratch spill (launch_bounds(1024)
// defaulted to a 64-VGPR cap; WRITE_SIZE 3MB->61MB). Now: launch_bounds(1024,4)
// (true occupancy is 1 block/CU = 4 waves/EU -> 128 VGPR cap) + 2-deep 8-load
// pipeline groups (32 VGPR staging) instead of a 64-reg monolith.

typedef float f4 __attribute__((ext_vector_type(4)));
typedef float f2 __attribute__((ext_vector_type(2)));

#define B_    4
#define TQ_   256
#define TV_   256
#define D_    512
#define U_    256
#define KDIM  512          // H == D == 512
#define MROWS 1024         // B*TQ == B*TV
#define BKP   32           // proj LDS K-tile
#define KQ    128          // proj K-split quarter
#define NSTEP (KQ / BKP)   // 4

#define C2LOG2E 2.8853900817779268f   // 2*log2(e)

// ws layout (f4 units of 65536 per 1024x256 buffer):
//   [0..3] Pq partials [q][u] | [4..7] PvT partials [u][vg] | [8] Eq | [9] EvT
#define PELEMS  262144
#define EQ_OFF  (8 * PELEMS)
#define EVT_OFF (9 * PELEMS)

#if __has_builtin(__builtin_amdgcn_exp2f)
#define EXP2F(x) __builtin_amdgcn_exp2f(x)
#else
#define EXP2F(x) exp2f(x)
#endif
#if __has_builtin(__builtin_amdgcn_rcpf)
#define RCPF(x) __builtin_amdgcn_rcpf(x)
#else
#define RCPF(x) (1.0f / (x))
#endif

// ---------------- K-split projection GEMMs ----------------
__global__ __launch_bounds__(256) void proj_partial(
    const float* __restrict__ query, const float* __restrict__ values,
    const float* __restrict__ W1, const float* __restrict__ W2,
    float* __restrict__ ws)
{
    const int proj = blockIdx.z;    // 0: Pq, 1: PvT
    const int ks   = blockIdx.y;    // K-quarter
    const int tile = blockIdx.x;    // 0..63

    __shared__ __align__(16) float As[BKP][68];
    __shared__ __align__(16) float Bs[BKP][68];

    const int tid = threadIdx.x;
    const int tx = tid & 15, ty = tid >> 4;
    const int trow = tid >> 2, tk = (tid & 3) * 8;   // T-path: 64 rows x 8 k
    const int dk = tid >> 3, dcol = (tid & 7) * 8;   // D-path: 32 k x 64 cols
    const int kb = ks * KQ;

    int m0, n0;
    const float* Tsrc;
    const float* Dsrc;
    if (proj == 0) {
        m0 = (tile >> 2) * 64;  n0 = (tile & 3) * 64;
        Tsrc = query  + (size_t)(m0 + trow) * KDIM + kb + tk;  // -> As[k][m]
        Dsrc = W1     + (size_t)(kb + dk) * U_ + n0 + dcol;    // -> Bs[k][n]
    } else {
        m0 = (tile & 3) * 64;   n0 = (tile >> 2) * 64;
        Tsrc = values + (size_t)(n0 + trow) * KDIM + kb + tk;  // -> Bs[k][n]
        Dsrc = W2     + (size_t)(kb + dk) * U_ + m0 + dcol;    // -> As[k][m]
    }

    f4 t0 = *(const f4*)(Tsrc);
    f4 t1 = *(const f4*)(Tsrc + 4);
    f4 d0 = *(const f4*)(Dsrc);
    f4 d1 = *(const f4*)(Dsrc + 4);

    float acc[4][4] = {};

    for (int s = 0; s < NSTEP; ++s) {
        __syncthreads();
        if (proj == 0) {
            #pragma unroll
            for (int j = 0; j < 4; ++j) {
                As[tk + j][trow]     = t0[j];
                As[tk + 4 + j][trow] = t1[j];
            }
            *(f4*)&Bs[dk][dcol]     = d0;
            *(f4*)&Bs[dk][dcol + 4] = d1;
        } else {
            #pragma unroll
            for (int j = 0; j < 4; ++j) {
                Bs[tk + j][trow]     = t0[j];
                Bs[tk + 4 + j][trow] = t1[j];
            }
            *(f4*)&As[dk][dcol]     = d0;
            *(f4*)&As[dk][dcol + 4] = d1;
        }
        __syncthreads();

        if (s + 1 < NSTEP) {   // prefetch next K-tile into regs
            const float* Tn = Tsrc + (s + 1) * BKP;
            const float* Dn = Dsrc + (size_t)(s + 1) * BKP * U_;
            t0 = *(const f4*)(Tn);
            t1 = *(const f4*)(Tn + 4);
            d0 = *(const f4*)(Dn);
            d1 = *(const f4*)(Dn + 4);
        }

        #pragma unroll
        for (int kk = 0; kk < BKP; ++kk) {
            f4 av = *(const f4*)&As[kk][ty * 4];
            f4 bv = *(const f4*)&Bs[kk][tx * 4];
            #pragma unroll
            for (int i = 0; i < 4; ++i)
                #pragma unroll
                for (int j = 0; j < 4; ++j)
                    acc[i][j] = fmaf(av[i], bv[j], acc[i][j]);
        }
    }

    const int cstride = proj ? MROWS : U_;
    float* P = ws + (size_t)(proj * 4 + ks) * PELEMS;
    #pragma unroll
    for (int i = 0; i < 4; ++i) {
        f4 o = {acc[i][0], acc[i][1], acc[i][2], acc[i][3]};
        *(f4*)&P[(size_t)(m0 + ty * 4 + i) * cstride + n0 + tx * 4] = o;
    }
}

// ---------------- combine: E = exp2(C * (sum of 4 partials + bias)) ----------
__global__ __launch_bounds__(256) void proj_combine(
    const float* __restrict__ b1, const float* __restrict__ b2,
    float* __restrict__ ws)
{
    const int g = blockIdx.x * 256 + threadIdx.x;   // 0..131071
    const int proj = g >> 16;
    const int rem  = g & 65535;
    f4* wsf4 = (f4*)ws;

    f4 p = wsf4[(size_t)(proj * 4)     * 65536 + rem];
    p   += wsf4[(size_t)(proj * 4 + 1) * 65536 + rem];
    p   += wsf4[(size_t)(proj * 4 + 2) * 65536 + rem];
    p   += wsf4[(size_t)(proj * 4 + 3) * 65536 + rem];

    f4 bias;
    if (proj == 0) {
        bias = ((const f4*)b1)[rem & 63];           // u = column
    } else {
        float bb = b2[rem >> 8];                    // u = row (256 f4/row)
        bias = f4{bb, bb, bb, bb};
    }

    f4 e;
    #pragma unroll
    for (int j = 0; j < 4; ++j)
        e[j] = EXP2F((p[j] + bias[j]) * C2LOG2E);

    wsf4[(size_t)(8 + proj) * 65536 + rem] = e;
}

// ---------------- fused score + softmax + context ----------------
// One block = (batch b, 4 q rows). 1024 threads (16 waves), 1 block/CU.
// launch_bounds(1024,4): 4 waves/EU -> 128-VGPR cap (NO spill; R6 lesson).
// Score: 2-deep pipelined 8-load groups from EvT (static reg bufs).
// Softmax: wave w < 4 handles q-row w. Context: dbuf values prefetch.
__global__ __launch_bounds__(1024, 4) void fused_attn(
    const float* __restrict__ values, const float* __restrict__ Vw,
    const float* __restrict__ ws, float* __restrict__ out)
{
    __shared__ __align__(16) f4    eqT[U_];          // {eq[q0+0..3]}[u]
    __shared__ __align__(16) float vw[U_];
    __shared__ __align__(16) float scr[8][4][TV_];   // [u-slice][q][v]

    const float* Eq  = ws + EQ_OFF;
    const float* EvT = ws + EVT_OFF;

    const int tid = threadIdx.x;
    const int b  = blockIdx.y;
    const int q0 = blockIdx.x * 4;

    if (tid < U_) {
        const int u = tid;
        const size_t base = (size_t)(b * TQ_ + q0) * U_ + u;   // 4 coalesced rows
        f4 e = {Eq[base], Eq[base + U_], Eq[base + 2 * U_], Eq[base + 3 * U_]};
        eqT[u] = e;
        vw[u]  = Vw[u];
    }

    const int v2 = tid & 127;        // owns v = {2*v2, 2*v2+1}
    const int us = tid >> 7;         // u-slice 0..7 (32 u each)
    const int SV = MROWS / 2;        // EvT f2 row stride
    const f2* evp = (const f2*)(EvT + (size_t)b * TV_) + v2
                    + (size_t)(us * 32) * SV;

    // stage group 0 (8 loads in flight) before the barrier
    f2 evA[8], evB[8];
    #pragma unroll
    for (int i = 0; i < 8; ++i) evA[i] = evp[(size_t)i * SV];

    __syncthreads();

    // ---- scores: p(q,v) = sum_u vw[u] * rcp(eq[q,u]*ev[v,u] + 1)
    {
        f2 acc[4] = {{0.f, 0.f}, {0.f, 0.f}, {0.f, 0.f}, {0.f, 0.f}};
        const int ub = us * 32;

        #define SCORE_GROUP(BUF, G)                                         \
            _Pragma("unroll")                                                \
            for (int i = 0; i < 8; ++i) {                                    \
                const int u = ub + (G) * 8 + i;                              \
                f4 eq = eqT[u];                                              \
                float w = vw[u];                                             \
                _Pragma("unroll")                                            \
                for (int q = 0; q < 4; ++q) {                                \
                    float den0 = fmaf(eq[q], BUF[i].x, 1.0f);                \
                    float den1 = fmaf(eq[q], BUF[i].y, 1.0f);                \
                    acc[q].x = fmaf(w, RCPF(den0), acc[q].x);                \
                    acc[q].y = fmaf(w, RCPF(den1), acc[q].y);                \
                }                                                            \
            }

        #pragma unroll
        for (int i = 0; i < 8; ++i) evB[i] = evp[(size_t)(8 + i) * SV];
        SCORE_GROUP(evA, 0)
        #pragma unroll
        for (int i = 0; i < 8; ++i) evA[i] = evp[(size_t)(16 + i) * SV];
        SCORE_GROUP(evB, 1)
        #pragma unroll
        for (int i = 0; i < 8; ++i) evB[i] = evp[(size_t)(24 + i) * SV];
        SCORE_GROUP(evA, 2)
        SCORE_GROUP(evB, 3)
        #undef SCORE_GROUP

        #pragma unroll
        for (int q = 0; q < 4; ++q)
            *(f2*)&scr[us][q][2 * v2] = acc[q];
    }
    __syncthreads();

    // ---- softmax over v: wave w in [0,4) handles q-row w
    {
        const int w = tid >> 6, lane = tid & 63;
        if (w < 4) {
            float p0 = 0.f, p1 = 0.f, p2 = 0.f, p3 = 0.f;
            #pragma unroll
            for (int s = 0; s < 8; ++s) {
                p0 += scr[s][w][lane];
                p1 += scr[s][w][lane + 64];
                p2 += scr[s][w][lane + 128];
                p3 += scr[s][w][lane + 192];
            }
            float m = fminf(fminf(p0, p1), fminf(p2, p3));  // max score = min p
            #pragma unroll
            for (int off = 32; off; off >>= 1) m = fminf(m, __shfl_xor(m, off));
            float e0 = EXP2F((m - p0) * C2LOG2E);
            float e1 = EXP2F((m - p1) * C2LOG2E);
            float e2 = EXP2F((m - p2) * C2LOG2E);
            float e3 = EXP2F((m - p3) * C2LOG2E);
            float sum = e0 + e1 + e2 + e3;
            #pragma unroll
            for (int off = 32; off; off >>= 1) sum += __shfl_xor(sum, off);
            const float rinv = 1.0f / sum;    // exact division
            e0 *= rinv; e1 *= rinv; e2 *= rinv; e3 *= rinv;
            scr[0][w][lane]       = e0;
            scr[0][w][lane + 64]  = e1;
            scr[0][w][lane + 128] = e2;
            scr[0][w][lane + 192] = e3;
            float* attn_out = out + (size_t)B_ * TQ_ * D_;
            const size_t rb = ((size_t)(b * TQ_ + q0 + w)) * TV_;
            attn_out[rb + lane]       = e0;
            attn_out[rb + lane + 64]  = e1;
            attn_out[rb + lane + 128] = e2;
            attn_out[rb + lane + 192] = e3;
        }
    }
    __syncthreads();

    // ---- context: quarter-block qh owns q-row qh; thread owns d-pair.
    // Double-buffered prefetch: 8 values-loads in flight while 16 FMAs retire.
    {
        const int qh = tid >> 8;
        const int d2 = tid & 255;
        const f2* vp = (const f2*)&values[(size_t)b * TV_ * D_] + d2;
        const float* arow = &scr[0][qh][0];

        f2 bufA[8], bufB[8];
        #pragma unroll
        for (int i = 0; i < 8; ++i) bufA[i] = vp[(size_t)i * (D_ / 2)];

        f2 acc = {0.f, 0.f};
        #pragma unroll
        for (int g = 0; g < 32; g += 2) {
            if (g + 1 < 32) {
                #pragma unroll
                for (int i = 0; i < 8; ++i)
                    bufB[i] = vp[(size_t)((g + 1) * 8 + i) * (D_ / 2)];
            }
            #pragma unroll
            for (int i = 0; i < 8; ++i)
                acc += arow[g * 8 + i] * bufA[i];
            if (g + 2 < 32) {
                #pragma unroll
                for (int i = 0; i < 8; ++i)
                    bufA[i] = vp[(size_t)((g + 2) * 8 + i) * (D_ / 2)];
            }
            #pragma unroll
            for (int i = 0; i < 8; ++i)
                acc += arow[(g + 1) * 8 + i] * bufB[i];
        }
        *(f2*)&out[((size_t)(b * TQ_ + q0 + qh)) * D_ + 2 * d2] = acc;
    }
}

extern "C" void kernel_launch(void* const* d_in, const int* in_sizes, int n_in,
                              void* d_out, int out_size, void* d_ws, size_t ws_size,
                              hipStream_t stream) {
    const float* query  = (const float*)d_in[0];
    const float* values = (const float*)d_in[1];
    const float* W1     = (const float*)d_in[2];
    const float* b1     = (const float*)d_in[3];
    const float* W2     = (const float*)d_in[4];
    const float* b2     = (const float*)d_in[5];
    const float* Vw     = (const float*)d_in[6];
    float* out = (float*)d_out;
    float* ws  = (float*)d_ws;

    proj_partial<<<dim3(64, 4, 2), 256, 0, stream>>>(query, values, W1, W2, ws);
    proj_combine<<<dim3(512), 256, 0, stream>>>(b1, b2, ws);
    fused_attn<<<dim3(TQ_ / 4, B_), 1024, 0, stream>>>(values, Vw, ws, out);
}

// Round 8
// 44.075 us; speedup vs baseline: 1.7351x; 1.5686x over previous
//
#include <hip/hip_runtime.h>
#include <math.h>

// Bahdanau attention, fp32. B=4, TQ=TV=256, H=D=512, U=256.
// out = [context (4*256*512)] ++ [attn (4*256*256)]
//
// tanh(x) = 1 - 2/(e^{2x}+1); e^{2(q+v)} = e^{2q}*e^{2v}.
// proj_partial: K-split GEMMs -> Pq[q][u] partials, PvT[u][vg] partials.
// proj_combine: E = exp2(C*(sum partials + bias)) for Eq and EvT.
// score_softmax: block=(b,2q) x 512 blocks (2/CU). 1 rcp + 2 fma per element,
//   per-u state as ONE f4 LDS broadcast, 8-deep dbuf EvT loads. Block softmax.
// context_gemm: block=(b,4q) x 256 blocks. attn packed f4[v] in LDS;
//   per v: 1 f2 values load + 1 b128 broadcast + 4 f2-fma; 8-deep dbuf.
//
// R8 rationale: the 16-wave monolith was 80% stalled (VALUBusy ~20%) at every
// occupancy/layout we tried; 1024-thr blocks also pin VGPR=64 (R6/R7 spills).
// Split kernels: small blocks, 2 independent blocks/CU, spill-free reg dbuf.

typedef float f4 __attribute__((ext_vector_type(4)));
typedef float f2 __attribute__((ext_vector_type(2)));

#define B_    4
#define TQ_   256
#define TV_   256
#define D_    512
#define U_    256
#define KDIM  512          // H == D == 512
#define MROWS 1024         // B*TQ == B*TV
#define BKP   32           // proj LDS K-tile
#define KQ    128          // proj K-split quarter
#define NSTEP (KQ / BKP)   // 4

#define C2LOG2E 2.8853900817779268f   // 2*log2(e)

// ws layout (f4 units of 65536 per 1024x256 buffer):
//   [0..3] Pq partials [q][u] | [4..7] PvT partials [u][vg] | [8] Eq | [9] EvT
#define PELEMS  262144
#define EQ_OFF  (8 * PELEMS)
#define EVT_OFF (9 * PELEMS)

#if __has_builtin(__builtin_amdgcn_exp2f)
#define EXP2F(x) __builtin_amdgcn_exp2f(x)
#else
#define EXP2F(x) exp2f(x)
#endif
#if __has_builtin(__builtin_amdgcn_rcpf)
#define RCPF(x) __builtin_amdgcn_rcpf(x)
#else
#define RCPF(x) (1.0f / (x))
#endif

// ---------------- K-split projection GEMMs (unchanged) ----------------
__global__ __launch_bounds__(256) void proj_partial(
    const float* __restrict__ query, const float* __restrict__ values,
    const float* __restrict__ W1, const float* __restrict__ W2,
    float* __restrict__ ws)
{
    const int proj = blockIdx.z;    // 0: Pq, 1: PvT
    const int ks   = blockIdx.y;    // K-quarter
    const int tile = blockIdx.x;    // 0..63

    __shared__ __align__(16) float As[BKP][68];
    __shared__ __align__(16) float Bs[BKP][68];

    const int tid = threadIdx.x;
    const int tx = tid & 15, ty = tid >> 4;
    const int trow = tid >> 2, tk = (tid & 3) * 8;   // T-path: 64 rows x 8 k
    const int dk = tid >> 3, dcol = (tid & 7) * 8;   // D-path: 32 k x 64 cols
    const int kb = ks * KQ;

    int m0, n0;
    const float* Tsrc;
    const float* Dsrc;
    if (proj == 0) {
        m0 = (tile >> 2) * 64;  n0 = (tile & 3) * 64;
        Tsrc = query  + (size_t)(m0 + trow) * KDIM + kb + tk;  // -> As[k][m]
        Dsrc = W1     + (size_t)(kb + dk) * U_ + n0 + dcol;    // -> Bs[k][n]
    } else {
        m0 = (tile & 3) * 64;   n0 = (tile >> 2) * 64;
        Tsrc = values + (size_t)(n0 + trow) * KDIM + kb + tk;  // -> Bs[k][n]
        Dsrc = W2     + (size_t)(kb + dk) * U_ + m0 + dcol;    // -> As[k][m]
    }

    f4 t0 = *(const f4*)(Tsrc);
    f4 t1 = *(const f4*)(Tsrc + 4);
    f4 d0 = *(const f4*)(Dsrc);
    f4 d1 = *(const f4*)(Dsrc + 4);

    float acc[4][4] = {};

    for (int s = 0; s < NSTEP; ++s) {
        __syncthreads();
        if (proj == 0) {
            #pragma unroll
            for (int j = 0; j < 4; ++j) {
                As[tk + j][trow]     = t0[j];
                As[tk + 4 + j][trow] = t1[j];
            }
            *(f4*)&Bs[dk][dcol]     = d0;
            *(f4*)&Bs[dk][dcol + 4] = d1;
        } else {
            #pragma unroll
            for (int j = 0; j < 4; ++j) {
                Bs[tk + j][trow]     = t0[j];
                Bs[tk + 4 + j][trow] = t1[j];
            }
            *(f4*)&As[dk][dcol]     = d0;
            *(f4*)&As[dk][dcol + 4] = d1;
        }
        __syncthreads();

        if (s + 1 < NSTEP) {   // prefetch next K-tile into regs
            const float* Tn = Tsrc + (s + 1) * BKP;
            const float* Dn = Dsrc + (size_t)(s + 1) * BKP * U_;
            t0 = *(const f4*)(Tn);
            t1 = *(const f4*)(Tn + 4);
            d0 = *(const f4*)(Dn);
            d1 = *(const f4*)(Dn + 4);
        }

        #pragma unroll
        for (int kk = 0; kk < BKP; ++kk) {
            f4 av = *(const f4*)&As[kk][ty * 4];
            f4 bv = *(const f4*)&Bs[kk][tx * 4];
            #pragma unroll
            for (int i = 0; i < 4; ++i)
                #pragma unroll
                for (int j = 0; j < 4; ++j)
                    acc[i][j] = fmaf(av[i], bv[j], acc[i][j]);
        }
    }

    const int cstride = proj ? MROWS : U_;
    float* P = ws + (size_t)(proj * 4 + ks) * PELEMS;
    #pragma unroll
    for (int i = 0; i < 4; ++i) {
        f4 o = {acc[i][0], acc[i][1], acc[i][2], acc[i][3]};
        *(f4*)&P[(size_t)(m0 + ty * 4 + i) * cstride + n0 + tx * 4] = o;
    }
}

// ---------------- combine: E = exp2(C * (sum of 4 partials + bias)) ----------
__global__ __launch_bounds__(256) void proj_combine(
    const float* __restrict__ b1, const float* __restrict__ b2,
    float* __restrict__ ws)
{
    const int g = blockIdx.x * 256 + threadIdx.x;   // 0..131071
    const int proj = g >> 16;
    const int rem  = g & 65535;
    f4* wsf4 = (f4*)ws;

    f4 p = wsf4[(size_t)(proj * 4)     * 65536 + rem];
    p   += wsf4[(size_t)(proj * 4 + 1) * 65536 + rem];
    p   += wsf4[(size_t)(proj * 4 + 2) * 65536 + rem];
    p   += wsf4[(size_t)(proj * 4 + 3) * 65536 + rem];

    f4 bias;
    if (proj == 0) {
        bias = ((const f4*)b1)[rem & 63];           // u = column
    } else {
        float bb = b2[rem >> 8];                    // u = row (256 f4/row)
        bias = f4{bb, bb, bb, bb};
    }

    f4 e;
    #pragma unroll
    for (int j = 0; j < 4; ++j)
        e[j] = EXP2F((p[j] + bias[j]) * C2LOG2E);

    wsf4[(size_t)(8 + proj) * 65536 + rem] = e;
}

// ---------------- score + softmax ----------------
// Block = (b, 2 q-rows), 256 threads (4 waves). Grid 512 -> 2 blocks/CU.
// Thread owns v = tid. p(q,v) = sum_u vw[u]*rcp(eq[q,u]*ev[v,u]+1).
// Per u: ONE f4 LDS broadcast {eq0,eq1,vw,-} + 1 pipelined EvT load
// + 2 fma + 2 rcp + 2 fma. Then block softmax (2 rows), write attn to out.
__global__ __launch_bounds__(256) void score_softmax(
    const float* __restrict__ Vw, const float* __restrict__ ws,
    float* __restrict__ out)
{
    __shared__ __align__(16) f4 epk[U_];      // {eq_q0, eq_q1, vw, 0}[u]
    __shared__ float redmin[4][2];
    __shared__ float redsum[4][2];

    const int tid = threadIdx.x;
    const int b  = blockIdx.y;
    const int q0 = blockIdx.x * 2;

    {
        const float* eqr = ws + EQ_OFF + (size_t)(b * TQ_ + q0) * U_;
        epk[tid] = f4{eqr[tid], eqr[U_ + tid], Vw[tid], 0.0f};
    }

    // EvT[u][vglobal]: thread's column, stride MROWS floats per u
    const float* evp = ws + EVT_OFF + (size_t)b * TV_ + tid;

    float evA[8], evB[8];
    #pragma unroll
    for (int i = 0; i < 8; ++i) evA[i] = evp[(size_t)i * MROWS];

    __syncthreads();

    float p0 = 0.f, p1 = 0.f;

    #define SGRP(BUF, G)                                                 \
        _Pragma("unroll")                                                \
        for (int i = 0; i < 8; ++i) {                                    \
            f4 t = epk[(G) * 8 + i];                                     \
            float d0 = fmaf(t.x, BUF[i], 1.0f);                          \
            float d1 = fmaf(t.y, BUF[i], 1.0f);                          \
            p0 = fmaf(t.z, RCPF(d0), p0);                                \
            p1 = fmaf(t.z, RCPF(d1), p1);                                \
        }

    #pragma unroll
    for (int g = 0; g < 32; g += 2) {
        #pragma unroll
        for (int i = 0; i < 8; ++i)
            evB[i] = evp[(size_t)((g + 1) * 8 + i) * MROWS];
        SGRP(evA, g)
        if (g + 2 < 32) {
            #pragma unroll
            for (int i = 0; i < 8; ++i)
                evA[i] = evp[(size_t)((g + 2) * 8 + i) * MROWS];
        }
        SGRP(evB, g + 1)
    }
    #undef SGRP

    // ---- softmax over v (score = const - 2p: max score = min p)
    const int w = tid >> 6, lane = tid & 63;
    float m0 = p0, m1 = p1;
    #pragma unroll
    for (int off = 32; off; off >>= 1) {
        m0 = fminf(m0, __shfl_xor(m0, off));
        m1 = fminf(m1, __shfl_xor(m1, off));
    }
    if (lane == 0) { redmin[w][0] = m0; redmin[w][1] = m1; }
    __syncthreads();
    m0 = fminf(fminf(redmin[0][0], redmin[1][0]), fminf(redmin[2][0], redmin[3][0]));
    m1 = fminf(fminf(redmin[0][1], redmin[1][1]), fminf(redmin[2][1], redmin[3][1]));

    float e0 = EXP2F((m0 - p0) * C2LOG2E);
    float e1 = EXP2F((m1 - p1) * C2LOG2E);

    float s0 = e0, s1 = e1;
    #pragma unroll
    for (int off = 32; off; off >>= 1) {
        s0 += __shfl_xor(s0, off);
        s1 += __shfl_xor(s1, off);
    }
    if (lane == 0) { redsum[w][0] = s0; redsum[w][1] = s1; }
    __syncthreads();
    s0 = redsum[0][0] + redsum[1][0] + redsum[2][0] + redsum[3][0];
    s1 = redsum[0][1] + redsum[1][1] + redsum[2][1] + redsum[3][1];

    float* attn = out + (size_t)B_ * TQ_ * D_ + (size_t)(b * TQ_ + q0) * TV_;
    attn[tid]       = e0 * (1.0f / s0);   // exact division
    attn[TV_ + tid] = e1 * (1.0f / s1);
}

// ---------------- context: attn @ values ----------------
// Block = (b, 4 q-rows), 256 threads. Thread owns d-pair (f2), loops all v.
// attn (from out) packed f4{q0..q3}[v] in LDS -> one b128 broadcast per v.
// values loads 8-deep double-buffered; values read ONCE per block (512 KB).
__global__ __launch_bounds__(256) void context_gemm(
    const float* __restrict__ values, float* __restrict__ out)
{
    __shared__ __align__(16) f4 apk[TV_];

    const int tid = threadIdx.x;
    const int b  = blockIdx.y;
    const int q0 = blockIdx.x * 4;

    const float* at = out + (size_t)B_ * TQ_ * D_ + (size_t)(b * TQ_ + q0) * TV_;
    apk[tid] = f4{at[tid], at[TV_ + tid], at[2 * TV_ + tid], at[3 * TV_ + tid]};

    const f2* vp = (const f2*)(values + (size_t)b * TV_ * D_) + tid;

    f2 bufA[8], bufB[8];
    #pragma unroll
    for (int i = 0; i < 8; ++i) bufA[i] = vp[(size_t)i * (D_ / 2)];

    __syncthreads();

    f2 acc0 = {0.f, 0.f}, acc1 = {0.f, 0.f}, acc2 = {0.f, 0.f}, acc3 = {0.f, 0.f};

    #define CGRP(BUF, G)                                                 \
        _Pragma("unroll")                                                \
        for (int i = 0; i < 8; ++i) {                                    \
            f4 a = apk[(G) * 8 + i];                                     \
            f2 val = BUF[i];                                             \
            acc0 += a.x * val;                                           \
            acc1 += a.y * val;                                           \
            acc2 += a.z * val;                                           \
            acc3 += a.w * val;                                           \
        }

    #pragma unroll
    for (int g = 0; g < 32; g += 2) {
        #pragma unroll
        for (int i = 0; i < 8; ++i)
            bufB[i] = vp[(size_t)((g + 1) * 8 + i) * (D_ / 2)];
        CGRP(bufA, g)
        if (g + 2 < 32) {
            #pragma unroll
            for (int i = 0; i < 8; ++i)
                bufA[i] = vp[(size_t)((g + 2) * 8 + i) * (D_ / 2)];
        }
        CGRP(bufB, g + 1)
    }
    #undef CGRP

    float* orow = out + (size_t)(b * TQ_ + q0) * D_ + 2 * tid;
    *(f2*)(orow)          = acc0;
    *(f2*)(orow + D_)     = acc1;
    *(f2*)(orow + 2 * D_) = acc2;
    *(f2*)(orow + 3 * D_) = acc3;
}

extern "C" void kernel_launch(void* const* d_in, const int* in_sizes, int n_in,
                              void* d_out, int out_size, void* d_ws, size_t ws_size,
                              hipStream_t stream) {
    const float* query  = (const float*)d_in[0];
    const float* values = (const float*)d_in[1];
    const float* W1     = (const float*)d_in[2];
    const float* b1     = (const float*)d_in[3];
    const float* W2     = (const float*)d_in[4];
    const float* b2     = (const float*)d_in[5];
    const float* Vw     = (const float*)d_in[6];
    float* out = (float*)d_out;
    float* ws  = (float*)d_ws;

    proj_partial<<<dim3(64, 4, 2), 256, 0, stream>>>(query, values, W1, W2, ws);
    proj_combine<<<dim3(512), 256, 0, stream>>>(b1, b2, ws);
    score_softmax<<<dim3(TQ_ / 2, B_), 256, 0, stream>>>(Vw, ws, out);
    context_gemm<<<dim3(TQ_ / 4, B_), 256, 0, stream>>>(values, out);
}

// Round 9
// 42.239 us; speedup vs baseline: 1.8105x; 1.0435x over previous
//
#include <hip/hip_runtime.h>
#include <math.h>

// Bahdanau attention, fp32. B=4, TQ=TV=256, H=D=512, U=256.
// out = [context (4*256*512)] ++ [attn (4*256*256)]
//
// tanh(x) = 1 - 2/(e^{2x}+1); e^{2(q+v)} = e^{2q}*e^{2v}.
// proj_mfma: bf16 MFMA GEMMs (error budget: bf16 inputs give context err
//   ~1e-4 << 5.6e-3 threshold) -> Eq[q][u], EvT[u][vg] with exp2 epilogue.
//   Replaces fp32 proj_partial + proj_combine (R8: ~10-12us) entirely.
// score_softmax / context_gemm: unchanged from R8 (single-variable round).

typedef float f4 __attribute__((ext_vector_type(4)));
typedef float f2 __attribute__((ext_vector_type(2)));
typedef __attribute__((ext_vector_type(8))) short s8v;            // 8 bf16
typedef __attribute__((ext_vector_type(8))) unsigned short u8v;

#define B_    4
#define TQ_   256
#define TV_   256
#define D_    512
#define U_    256
#define KDIM  512          // H == D == 512
#define MROWS 1024         // B*TQ == B*TV

#define C2LOG2E 2.8853900817779268f   // 2*log2(e)

// ws layout (floats): Eq [1024][256] at 0 | EvT [256][1024] at 262144
#define EQ_OFF  0
#define EVT_OFF 262144

#if __has_builtin(__builtin_amdgcn_exp2f)
#define EXP2F(x) __builtin_amdgcn_exp2f(x)
#else
#define EXP2F(x) exp2f(x)
#endif
#if __has_builtin(__builtin_amdgcn_rcpf)
#define RCPF(x) __builtin_amdgcn_rcpf(x)
#else
#define RCPF(x) (1.0f / (x))
#endif

__device__ __forceinline__ unsigned short f2bf(float f) {   // RNE f32->bf16
    union { float f; unsigned u; } v; v.f = f;
    return (unsigned short)((v.u + 0x7FFF + ((v.u >> 16) & 1)) >> 16);
}

// ---------------- bf16 MFMA projection GEMMs + exp2 epilogue ----------------
// blockIdx.y = proj. 64x64 output tile, 256 thr (4 waves), K=512 (16 steps
// of 32), double-buffered LDS, register prefetch.
//   proj0: Eq[m][u]  = exp2(C*(query[m][k] @ W1[k][u] + b1[u]))
//   proj1: EvT[u][v] = exp2(C*(W2[k][u]^T @ values[v][k]^T + b2[u]))
// LDS tiles [64 rows][40 bf16] (80B rows: b128 frag reads spread 8 start-
// groups x 4 banks = all 32 banks uniformly). A_lds rows = M, B_lds rows = N;
// both K-contiguous. Frag layout (16x16x32): A[row=l&15][k=(l>>4)*8+j],
// B[k=(l>>4)*8+j][col=l&15]; C/D: col=l&15, row=(l>>4)*4+reg (m89-verified).
__global__ __launch_bounds__(256) void proj_mfma(
    const float* __restrict__ query, const float* __restrict__ values,
    const float* __restrict__ W1, const float* __restrict__ b1,
    const float* __restrict__ W2, const float* __restrict__ b2,
    float* __restrict__ ws)
{
    __shared__ unsigned short Al[2][64][40];
    __shared__ unsigned short Bl[2][64][40];

    const int tid  = threadIdx.x;
    const int proj = blockIdx.y;
    const int x    = blockIdx.x;

    int m0, n0;
    if (proj == 0) { m0 = (x >> 2) * 64; n0 = (x & 3) * 64; }
    else           { m0 = (x & 3) * 64;  n0 = (x >> 2) * 64; }

    const int sr = tid >> 2;          // staging row 0..63
    const int sk = (tid & 3) * 8;     // k-segment

    // direct src (K-contiguous rows): proj0 query[m0+sr], proj1 values[n0+sr]
    const float* dptr = (proj ? values + (size_t)(n0 + sr) * KDIM
                              : query  + (size_t)(m0 + sr) * KDIM) + sk;
    // trans src (columns of W): proj0 W1[.][n0+sr], proj1 W2[.][m0+sr]
    const float* tptr = (proj ? W2 + (m0 + sr) : W1 + (n0 + sr))
                        + (size_t)sk * U_;

    f4 d0, d1;
    float tv0, tv1, tv2, tv3, tv4, tv5, tv6, tv7;

#define LOADR(S)                                                        \
    do {                                                                \
        const float* dp = dptr + (size_t)(S) * 32;                      \
        d0 = *(const f4*)(dp);                                          \
        d1 = *(const f4*)(dp + 4);                                      \
        const float* tp = tptr + (size_t)(S) * 32 * U_;                 \
        tv0 = tp[0];       tv1 = tp[U_];       tv2 = tp[2 * U_];        \
        tv3 = tp[3 * U_];  tv4 = tp[4 * U_];   tv5 = tp[5 * U_];        \
        tv6 = tp[6 * U_];  tv7 = tp[7 * U_];                            \
    } while (0)

#define WRITEB(BUF)                                                     \
    do {                                                                \
        u8v dd, tt;                                                     \
        dd[0] = f2bf(d0[0]); dd[1] = f2bf(d0[1]);                       \
        dd[2] = f2bf(d0[2]); dd[3] = f2bf(d0[3]);                       \
        dd[4] = f2bf(d1[0]); dd[5] = f2bf(d1[1]);                       \
        dd[6] = f2bf(d1[2]); dd[7] = f2bf(d1[3]);                       \
        tt[0] = f2bf(tv0); tt[1] = f2bf(tv1); tt[2] = f2bf(tv2);        \
        tt[3] = f2bf(tv3); tt[4] = f2bf(tv4); tt[5] = f2bf(tv5);        \
        tt[6] = f2bf(tv6); tt[7] = f2bf(tv7);                           \
        unsigned short* ddst = proj ? &Bl[BUF][sr][sk] : &Al[BUF][sr][sk]; \
        unsigned short* tdst = proj ? &Al[BUF][sr][sk] : &Bl[BUF][sr][sk]; \
        *(u8v*)ddst = dd;                                               \
        *(u8v*)tdst = tt;                                               \
    } while (0)

    f4 acc0 = {}, acc1 = {}, acc2 = {}, acc3 = {};

    const int w  = tid >> 6;          // wave 0..3 -> rows w*16..+15
    const int l  = tid & 63;
    const int fr = l & 15;
    const int fk = (l >> 4) * 8;

    LOADR(0);
    WRITEB(0);

    for (int s = 0; s < 16; ++s) {
        __syncthreads();
        if (s + 1 < 16) LOADR(s + 1);
        {
            const int bu = s & 1;
            s8v af  = *(const s8v*)&Al[bu][w * 16 + fr][fk];
            s8v bf0 = *(const s8v*)&Bl[bu][fr][fk];
            s8v bf1 = *(const s8v*)&Bl[bu][16 + fr][fk];
            s8v bf2 = *(const s8v*)&Bl[bu][32 + fr][fk];
            s8v bf3 = *(const s8v*)&Bl[bu][48 + fr][fk];
            acc0 = __builtin_amdgcn_mfma_f32_16x16x32_bf16(af, bf0, acc0, 0, 0, 0);
            acc1 = __builtin_amdgcn_mfma_f32_16x16x32_bf16(af, bf1, acc1, 0, 0, 0);
            acc2 = __builtin_amdgcn_mfma_f32_16x16x32_bf16(af, bf2, acc2, 0, 0, 0);
            acc3 = __builtin_amdgcn_mfma_f32_16x16x32_bf16(af, bf3, acc3, 0, 0, 0);
        }
        if (s + 1 < 16) WRITEB((s + 1) & 1);
    }
#undef LOADR
#undef WRITEB

    // epilogue: exp2(C*(acc + bias)); C/D: col=l&15, row=(l>>4)*4+r
    const int orow  = m0 + w * 16 + (l >> 4) * 4;
    const int ocol0 = n0 + (l & 15);

    if (proj == 0) {
        float* E = ws + EQ_OFF;       // Eq[1024][256]
        #pragma unroll
        for (int nt = 0; nt < 4; ++nt) {
            const int n = ocol0 + nt * 16;
            const float bias = b1[n];
            const f4 a = nt == 0 ? acc0 : nt == 1 ? acc1 : nt == 2 ? acc2 : acc3;
            #pragma unroll
            for (int r = 0; r < 4; ++r)
                E[(size_t)(orow + r) * U_ + n] =
                    EXP2F((a[r] + bias) * C2LOG2E);
        }
    } else {
        float* E = ws + EVT_OFF;      // EvT[256][1024]
        #pragma unroll
        for (int nt = 0; nt < 4; ++nt) {
            const int n = ocol0 + nt * 16;
            const f4 a = nt == 0 ? acc0 : nt == 1 ? acc1 : nt == 2 ? acc2 : acc3;
            #pragma unroll
            for (int r = 0; r < 4; ++r)
                E[(size_t)(orow + r) * MROWS + n] =
                    EXP2F((a[r] + b2[orow + r]) * C2LOG2E);
        }
    }
}

// ---------------- score + softmax (unchanged from R8) ----------------
// Block = (b, 2 q-rows), 256 threads. Grid 512 -> 2 blocks/CU.
__global__ __launch_bounds__(256) void score_softmax(
    const float* __restrict__ Vw, const float* __restrict__ ws,
    float* __restrict__ out)
{
    __shared__ __align__(16) f4 epk[U_];      // {eq_q0, eq_q1, vw, 0}[u]
    __shared__ float redmin[4][2];
    __shared__ float redsum[4][2];

    const int tid = threadIdx.x;
    const int b  = blockIdx.y;
    const int q0 = blockIdx.x * 2;

    {
        const float* eqr = ws + EQ_OFF + (size_t)(b * TQ_ + q0) * U_;
        epk[tid] = f4{eqr[tid], eqr[U_ + tid], Vw[tid], 0.0f};
    }

    const float* evp = ws + EVT_OFF + (size_t)b * TV_ + tid;

    float evA[8], evB[8];
    #pragma unroll
    for (int i = 0; i < 8; ++i) evA[i] = evp[(size_t)i * MROWS];

    __syncthreads();

    float p0 = 0.f, p1 = 0.f;

    #define SGRP(BUF, G)                                                 \
        _Pragma("unroll")                                                \
        for (int i = 0; i < 8; ++i) {                                    \
            f4 t = epk[(G) * 8 + i];                                     \
            float d0 = fmaf(t.x, BUF[i], 1.0f);                          \
            float d1 = fmaf(t.y, BUF[i], 1.0f);                          \
            p0 = fmaf(t.z, RCPF(d0), p0);                                \
            p1 = fmaf(t.z, RCPF(d1), p1);                                \
        }

    #pragma unroll
    for (int g = 0; g < 32; g += 2) {
        #pragma unroll
        for (int i = 0; i < 8; ++i)
            evB[i] = evp[(size_t)((g + 1) * 8 + i) * MROWS];
        SGRP(evA, g)
        if (g + 2 < 32) {
            #pragma unroll
            for (int i = 0; i < 8; ++i)
                evA[i] = evp[(size_t)((g + 2) * 8 + i) * MROWS];
        }
        SGRP(evB, g + 1)
    }
    #undef SGRP

    // softmax over v (score = const - 2p: max score = min p)
    const int w = tid >> 6, lane = tid & 63;
    float m0 = p0, m1 = p1;
    #pragma unroll
    for (int off = 32; off; off >>= 1) {
        m0 = fminf(m0, __shfl_xor(m0, off));
        m1 = fminf(m1, __shfl_xor(m1, off));
    }
    if (lane == 0) { redmin[w][0] = m0; redmin[w][1] = m1; }
    __syncthreads();
    m0 = fminf(fminf(redmin[0][0], redmin[1][0]), fminf(redmin[2][0], redmin[3][0]));
    m1 = fminf(fminf(redmin[0][1], redmin[1][1]), fminf(redmin[2][1], redmin[3][1]));

    float e0 = EXP2F((m0 - p0) * C2LOG2E);
    float e1 = EXP2F((m1 - p1) * C2LOG2E);

    float s0 = e0, s1 = e1;
    #pragma unroll
    for (int off = 32; off; off >>= 1) {
        s0 += __shfl_xor(s0, off);
        s1 += __shfl_xor(s1, off);
    }
    if (lane == 0) { redsum[w][0] = s0; redsum[w][1] = s1; }
    __syncthreads();
    s0 = redsum[0][0] + redsum[1][0] + redsum[2][0] + redsum[3][0];
    s1 = redsum[0][1] + redsum[1][1] + redsum[2][1] + redsum[3][1];

    float* attn = out + (size_t)B_ * TQ_ * D_ + (size_t)(b * TQ_ + q0) * TV_;
    attn[tid]       = e0 * (1.0f / s0);   // exact division
    attn[TV_ + tid] = e1 * (1.0f / s1);
}

// ---------------- context: attn @ values (unchanged from R8) ----------------
__global__ __launch_bounds__(256) void context_gemm(
    const float* __restrict__ values, float* __restrict__ out)
{
    __shared__ __align__(16) f4 apk[TV_];

    const int tid = threadIdx.x;
    const int b  = blockIdx.y;
    const int q0 = blockIdx.x * 4;

    const float* at = out + (size_t)B_ * TQ_ * D_ + (size_t)(b * TQ_ + q0) * TV_;
    apk[tid] = f4{at[tid], at[TV_ + tid], at[2 * TV_ + tid], at[3 * TV_ + tid]};

    const f2* vp = (const f2*)(values + (size_t)b * TV_ * D_) + tid;

    f2 bufA[8], bufB[8];
    #pragma unroll
    for (int i = 0; i < 8; ++i) bufA[i] = vp[(size_t)i * (D_ / 2)];

    __syncthreads();

    f2 acc0 = {0.f, 0.f}, acc1 = {0.f, 0.f}, acc2 = {0.f, 0.f}, acc3 = {0.f, 0.f};

    #define CGRP(BUF, G)                                                 \
        _Pragma("unroll")                                                \
        for (int i = 0; i < 8; ++i) {                                    \
            f4 a = apk[(G) * 8 + i];                                     \
            f2 val = BUF[i];                                             \
            acc0 += a.x * val;                                           \
            acc1 += a.y * val;                                           \
            acc2 += a.z * val;                                           \
            acc3 += a.w * val;                                           \
        }

    #pragma unroll
    for (int g = 0; g < 32; g += 2) {
        #pragma unroll
        for (int i = 0; i < 8; ++i)
            bufB[i] = vp[(size_t)((g + 1) * 8 + i) * (D_ / 2)];
        CGRP(bufA, g)
        if (g + 2 < 32) {
            #pragma unroll
            for (int i = 0; i < 8; ++i)
                bufA[i] = vp[(size_t)((g + 2) * 8 + i) * (D_ / 2)];
        }
        CGRP(bufB, g + 1)
    }
    #undef CGRP

    float* orow = out + (size_t)(b * TQ_ + q0) * D_ + 2 * tid;
    *(f2*)(orow)          = acc0;
    *(f2*)(orow + D_)     = acc1;
    *(f2*)(orow + 2 * D_) = acc2;
    *(f2*)(orow + 3 * D_) = acc3;
}

extern "C" void kernel_launch(void* const* d_in, const int* in_sizes, int n_in,
                              void* d_out, int out_size, void* d_ws, size_t ws_size,
                              hipStream_t stream) {
    const float* query  = (const float*)d_in[0];
    const float* values = (const float*)d_in[1];
    const float* W1     = (const float*)d_in[2];
    const float* b1     = (const float*)d_in[3];
    const float* W2     = (const float*)d_in[4];
    const float* b2     = (const float*)d_in[5];
    const float* Vw     = (const float*)d_in[6];
    float* out = (float*)d_out;
    float* ws  = (float*)d_ws;

    proj_mfma<<<dim3(64, 2), 256, 0, stream>>>(query, values, W1, b1, W2, b2, ws);
    score_softmax<<<dim3(TQ_ / 2, B_), 256, 0, stream>>>(Vw, ws, out);
    context_gemm<<<dim3(TQ_ / 4, B_), 256, 0, stream>>>(values, out);
}